// Round 3
// baseline (320.344 us; speedup 1.0000x reference)
//
#include <hip/hip_runtime.h>
#include <hip/hip_bf16.h>
#include <stdint.h>
#include <stddef.h>

// DCNv2 forward: B=4, H=W=96, C=256, F=256, K=9 (3x3, same, stride1, dil1), DG=1.
// R2: k_gemm 128x64 tiles (576->1152 blocks; was grid-starved at 2.25 blk/CU, occ 20%);
//     k_omgemm 3-way split-K by kh (288->864 blocks) + fp32 atomic epilogue into zeroed pOm.
// Pipeline: [k_pad]    x fp32 -> xp bf16 [4][98][98][256] with zero halo
//           [k_omw]    om weights -> wom bf16 [32][2304]
//           [k_wt]     main weight -> wt bf16 [256][2304]
//           [memset]   pOm = 0
//           [k_omgemm] MFMA GEMM M=36864 N=32 K=768 x3 splits -> atomicAdd pOm fp32 [NP][32]
//           [k_sample] offsets/mask + bilinear sample (bf16x2 gathers) -> cols bf16 [NP][2304]
//           [k_gemm]   128x64 bf16 MFMA GEMM + bias -> out fp32

namespace {
constexpr int H  = 96, W = 96, C = 256, F = 256;
constexpr int HP = 98;            // padded spatial dim (1-px zero halo)
constexpr int NP = 4 * 96 * 96;   // 36864 output pixels
constexpr int KC = 9 * 256;       // 2304 = GEMM K
}

typedef __attribute__((ext_vector_type(8))) short bf16x8;
typedef __attribute__((ext_vector_type(4))) float floatx4;

__device__ __forceinline__ void load_lds16(const void* g, void* l) {
  __builtin_amdgcn_global_load_lds((const __attribute__((address_space(1))) void*)g,
                                   (__attribute__((address_space(3))) void*)l,
                                   16, 0, 0);
}

__device__ __forceinline__ unsigned short bf16bits(float f) {
  __hip_bfloat16 h = __float2bfloat16(f);
  return *reinterpret_cast<unsigned short*>(&h);
}

// ---------------- k_pad: x fp32 -> xp bf16 with zero halo ----------------
__global__ __launch_bounds__(256) void k_pad(const float* __restrict__ x,
                                             __hip_bfloat16* __restrict__ xp) {
  const int pp = blockIdx.x;            // 0 .. 4*98*98-1
  const int c  = threadIdx.x;
  const int b  = pp / (HP * HP);
  const int r  = pp % (HP * HP);
  const int y  = r / HP, xq = r % HP;
  float v = 0.f;
  if (y >= 1 && y <= H && xq >= 1 && xq <= W)
    v = x[((size_t)((b * H + (y - 1)) * W + (xq - 1))) * C + c];
  xp[(size_t)pp * C + c] = __float2bfloat16(v);
}

// ---------------- k_omw: omk [9*256][27] -> wom [32][2304] bf16, zero-pad rows ----------------
__global__ __launch_bounds__(256) void k_omw(const float* __restrict__ omk,
                                             __hip_bfloat16* __restrict__ wom) {
  const int kk = blockIdx.x;   // 0..8
  const int oc = blockIdx.y;   // 0..31
  const int c  = threadIdx.x;  // 0..255
  float v = (oc < 27) ? omk[(size_t)(kk * 256 + c) * 27 + oc] : 0.f;
  wom[(size_t)oc * KC + kk * 256 + c] = __float2bfloat16(v);
}

// ---------------- k_wt: kern [KC][F] fp32 -> wt [F][KC] bf16 ----------------
__global__ __launch_bounds__(256) void k_wt(const float* __restrict__ kern,
                                            __hip_bfloat16* __restrict__ wt) {
  const int kc = blockIdx.x;    // 0..2303
  const int f  = threadIdx.x;   // 0..255
  wt[(size_t)f * KC + kc] = __float2bfloat16(kern[(size_t)kc * F + f]);
}

// ---------------- k_omgemm: implicit-im2col MFMA GEMM, tile 128(M) x 32(N), split-K x3 ----------------
// split s handles kk in {3s, 3s+1, 3s+2}; partials atomically added into pOm fp32 [NP][32].
__global__ __launch_bounds__(256) void k_omgemm(const __hip_bfloat16* __restrict__ xp,
                                                const __hip_bfloat16* __restrict__ wom,
                                                float* __restrict__ pOm) {
  __shared__ __align__(16) char lds[10240];  // A [128][32]bf16 @0 (8KB), B [32][32]bf16 @8192 (2KB)
  const int tid  = threadIdx.x;
  const int m0   = blockIdx.x * 128;
  const int s    = blockIdx.y;               // K-split 0..2
  const int lane = tid & 63, wave = tid >> 6;
  const int quad = lane >> 4, l16 = lane & 15;

  const int kp = tid & 3;
  const __hip_bfloat16* abase[2];
#pragma unroll
  for (int j = 0; j < 2; ++j) {
    const int row = (tid >> 2) + j * 64;
    const int p = m0 + row;
    const int b = p / (H * W);
    const int hw = p % (H * W);
    const int h = hw / W, w = hw % W;
    abase[j] = xp + ((size_t)(b * HP + h) * HP + w) * C + kp * 8;
  }
  const __hip_bfloat16* bbase = wom + (size_t)(tid >> 2) * KC + kp * 8;  // tid<128 only

  floatx4 acc[2][2];
#pragma unroll
  for (int i = 0; i < 2; ++i)
#pragma unroll
    for (int j = 0; j < 2; ++j) acc[i][j] = (floatx4){0.f, 0.f, 0.f, 0.f};

  const int kbeg = s * 768;
#pragma unroll 1
  for (int k0 = kbeg; k0 < kbeg + 768; k0 += 32) {
    const int kk = k0 >> 8;                 // 32-chunks never straddle a kk boundary
    const int c0 = k0 & 255;
    const int kh = kk / 3, kw = kk % 3;
    const int aoff = (kh * HP + kw) * C + c0;  // wave-uniform

    __syncthreads();
    load_lds16(abase[0] + aoff, &lds[tid * 16]);
    load_lds16(abase[1] + aoff, &lds[4096 + tid * 16]);
    if (tid < 128) load_lds16(bbase + k0, &lds[8192 + tid * 16]);
    __syncthreads();

    bf16x8 af[2], bfr[2];
#pragma unroll
    for (int mt = 0; mt < 2; ++mt)
      af[mt] = *(const bf16x8*)&lds[((wave * 32 + mt * 16 + l16) * 32 + quad * 8) * 2];
#pragma unroll
    for (int nt = 0; nt < 2; ++nt)
      bfr[nt] = *(const bf16x8*)&lds[8192 + ((nt * 16 + l16) * 32 + quad * 8) * 2];
#pragma unroll
    for (int mt = 0; mt < 2; ++mt)
#pragma unroll
      for (int nt = 0; nt < 2; ++nt)
        acc[mt][nt] = __builtin_amdgcn_mfma_f32_16x16x32_bf16(af[mt], bfr[nt], acc[mt][nt], 0, 0, 0);
  }

#pragma unroll
  for (int mt = 0; mt < 2; ++mt)
#pragma unroll
    for (int nt = 0; nt < 2; ++nt) {
      const int gm = m0 + wave * 32 + mt * 16 + quad * 4;
      const int gn = nt * 16 + l16;
#pragma unroll
      for (int r = 0; r < 4; ++r)
        __hip_atomic_fetch_add(&pOm[(size_t)(gm + r) * 32 + gn], acc[mt][nt][r],
                               __ATOMIC_RELAXED, __HIP_MEMORY_SCOPE_AGENT);
    }
}

// ---------------- k_sample: 2 pixels/block, 2 channels/thread (bf16x2) ----------------
__global__ __launch_bounds__(256) void k_sample(const __hip_bfloat16* __restrict__ xp,
                                                const float* __restrict__ pOm,
                                                const float* __restrict__ om_bias,
                                                __hip_bfloat16* __restrict__ cols) {
  const int tid = threadIdx.x;
  const int sub = tid >> 7, cid = tid & 127;       // pixel-in-block, channel-pair
  const int p   = blockIdx.x * 2 + sub;
  const int b   = p / (H * W);
  const int hw  = p % (H * W);
  const int h = hw / W, w = hw % W;

  __shared__ float s_py[2][9], s_px[2][9], s_m[2][9];
  if (cid < 9) {
    const int k = cid;
    const float dy = om_bias[2 * k]     + pOm[(size_t)p * 32 + 2 * k];
    const float dx = om_bias[2 * k + 1] + pOm[(size_t)p * 32 + 2 * k + 1];
    const float mv = om_bias[18 + k]    + pOm[(size_t)p * 32 + 18 + k];
    s_py[sub][k] = (float)(h - 1 + k / 3) + dy;
    s_px[sub][k] = (float)(w - 1 + k % 3) + dx;
    s_m[sub][k]  = 2.f / (1.f + __expf(-mv));
  }
  __syncthreads();

  const uint32_t* __restrict__ xb = (const uint32_t*)(xp + (size_t)b * (HP * HP * C)) + cid;
  uint32_t* __restrict__ ob = (uint32_t*)(cols + (size_t)p * KC) + cid;

#pragma unroll 1
  for (int k = 0; k < 9; ++k) {
    const float py = s_py[sub][k], px = s_px[sub][k], m = s_m[sub][k];
    const float y0f = floorf(py), x0f = floorf(px);
    const float fy = py - y0f, fx = px - x0f;
    const int y0 = (int)y0f, x0 = (int)x0f;
    float v0 = 0.f, v1 = 0.f;
#pragma unroll
    for (int dy2 = 0; dy2 < 2; ++dy2) {
#pragma unroll
      for (int dx2 = 0; dx2 < 2; ++dx2) {
        const int yi = y0 + dy2, xi = x0 + dx2;
        const bool valid = (yi >= 0) & (yi < H) & (xi >= 0) & (xi < W);
        const float wgt = valid ? (dy2 ? fy : 1.f - fy) * (dx2 ? fx : 1.f - fx) : 0.f;
        const int yc = min(max(yi + 1, 0), HP - 1);
        const int xc = min(max(xi + 1, 0), HP - 1);
        const uint32_t v = xb[(size_t)(yc * HP + xc) * 128];
        v0 += wgt * __uint_as_float(v << 16);
        v1 += wgt * __uint_as_float(v & 0xffff0000u);
      }
    }
    const uint32_t packed = (uint32_t)bf16bits(v0 * m) | ((uint32_t)bf16bits(v1 * m) << 16);
    ob[k * 128] = packed;
  }
}

// ---------------- k_gemm: bf16 MFMA GEMM, 128(M) x 64(N) tile ----------------
__global__ __launch_bounds__(256) void k_gemm(const __hip_bfloat16* __restrict__ A,
                                              const __hip_bfloat16* __restrict__ Bt,
                                              const float* __restrict__ bias,
                                              float* __restrict__ out) {
  __shared__ __align__(16) char lds[12288];   // A [128][32] @0 (8KB), B [64][32] @8192 (4KB)

  const int tid  = threadIdx.x;
  const int m0   = blockIdx.x * 128;
  const int n0   = blockIdx.y * 64;
  const int lane = tid & 63, wave = tid >> 6;
  const int wm = wave & 1, wn = wave >> 1;    // waves: 2 (m) x 2 (n); wave = 64M x 32N
  const int quad = lane >> 4, l16 = lane & 15;

  floatx4 acc[4][2];
#pragma unroll
  for (int i = 0; i < 4; ++i)
#pragma unroll
    for (int j = 0; j < 2; ++j) acc[i][j] = (floatx4){0.f, 0.f, 0.f, 0.f};

#pragma unroll 1
  for (int k0 = 0; k0 < KC; k0 += 32) {
    __syncthreads();
    {
      // A tile: 512 x 16B chunks (j=0,1), B tile: 256 x 16B chunks (j=2)
      const int rowA0 = tid >> 2, kpA = tid & 3;
      load_lds16(A + (size_t)(m0 + rowA0)      * KC + k0 + kpA * 8, &lds[tid * 16]);
      load_lds16(A + (size_t)(m0 + rowA0 + 64) * KC + k0 + kpA * 8, &lds[4096 + tid * 16]);
      load_lds16(Bt + (size_t)(n0 + rowA0)     * KC + k0 + kpA * 8, &lds[8192 + tid * 16]);
    }
    __syncthreads();

    bf16x8 af[4], bfr[2];
#pragma unroll
    for (int mt = 0; mt < 4; ++mt)
      af[mt] = *(const bf16x8*)&lds[((wm * 64 + mt * 16 + l16) * 32 + quad * 8) * 2];
#pragma unroll
    for (int nt = 0; nt < 2; ++nt)
      bfr[nt] = *(const bf16x8*)&lds[8192 + ((wn * 32 + nt * 16 + l16) * 32 + quad * 8) * 2];
#pragma unroll
    for (int mt = 0; mt < 4; ++mt)
#pragma unroll
      for (int nt = 0; nt < 2; ++nt)
        acc[mt][nt] = __builtin_amdgcn_mfma_f32_16x16x32_bf16(af[mt], bfr[nt], acc[mt][nt], 0, 0, 0);
  }

  // epilogue: C/D layout col=lane&15, row=quad*4+reg, + bias
#pragma unroll
  for (int mt = 0; mt < 4; ++mt) {
#pragma unroll
    for (int nt = 0; nt < 2; ++nt) {
      const int gm = m0 + wm * 64 + mt * 16 + quad * 4;
      const int gn = n0 + wn * 32 + nt * 16 + l16;
      const float bs = bias[gn];
#pragma unroll
      for (int r = 0; r < 4; ++r)
        out[(size_t)(gm + r) * F + gn] = acc[mt][nt][r] + bs;
    }
  }
}

extern "C" void kernel_launch(void* const* d_in, const int* in_sizes, int n_in,
                              void* d_out, int out_size, void* d_ws, size_t ws_size,
                              hipStream_t stream) {
  const float* x    = (const float*)d_in[0];   // [4,96,96,256]
  const float* omk  = (const float*)d_in[1];   // [3,3,256,27]
  const float* omb  = (const float*)d_in[2];   // [27]
  const float* kern = (const float*)d_in[3];   // [2304,256]
  const float* bias = (const float*)d_in[4];   // [256]
  float* out = (float*)d_out;                  // [4,96,96,256]

  char* ws = (char*)d_ws;
  size_t off = 0;
  __hip_bfloat16* wt   = (__hip_bfloat16*)(ws + off); off += (size_t)F * KC * 2;           // 1,179,648
  __hip_bfloat16* xp   = (__hip_bfloat16*)(ws + off); off += (size_t)4 * HP * HP * C * 2;  // 19,668,992
  __hip_bfloat16* wom  = (__hip_bfloat16*)(ws + off); off += (size_t)32 * KC * 2;          // 147,456
  float*          pOm  = (float*)(ws + off);          off += (size_t)NP * 32 * 4;          // 4,718,592
  __hip_bfloat16* cols = (__hip_bfloat16*)(ws + off);                                      // 169,869,312

  k_pad   <<<dim3(4 * HP * HP), 256, 0, stream>>>(x, xp);
  k_omw   <<<dim3(9, 32),       256, 0, stream>>>(omk, wom);
  k_wt    <<<dim3(KC),          256, 0, stream>>>(kern, wt);
  hipMemsetAsync(pOm, 0, (size_t)NP * 32 * 4, stream);
  k_omgemm<<<dim3(NP / 128, 3), 256, 0, stream>>>(xp, wom, pOm);
  k_sample<<<dim3(NP / 2),      256, 0, stream>>>(xp, pOm, omb, cols);
  k_gemm  <<<dim3(NP / 128, F / 64), 256, 0, stream>>>(cols, wt, bias, out);
}

// Round 4
// 250.514 us; speedup vs baseline: 1.2787x; 1.2787x over previous
//
#include <hip/hip_runtime.h>
#include <hip/hip_bf16.h>
#include <stdint.h>
#include <stddef.h>

// DCNv2 forward: B=4, H=W=96, C=256, F=256, K=9 (3x3, same, stride1, dil1), DG=1.
// R3 post-mortem: 128x64 tiles regressed (FETCH 88->126MB, chunks/MFMA 16->24). Real R2
//   limiter was imbalance (576 blocks = 2.25/CU -> 1.33x critical path).
// R4: k_gemm 96x128 tiles -> 768 blocks = 3.0/CU exact, intensity 18.7 chunks/MFMA;
//     k_sample 4ch/thread uint2; k_pad float4->uint2; k_wt LDS transpose; k_omgemm split-6.

namespace {
constexpr int H  = 96, W = 96, C = 256, F = 256;
constexpr int HP = 98;            // padded spatial dim (1-px zero halo)
constexpr int NP = 4 * 96 * 96;   // 36864 output pixels
constexpr int KC = 9 * 256;       // 2304 = GEMM K
}

typedef __attribute__((ext_vector_type(8))) short bf16x8;
typedef __attribute__((ext_vector_type(4))) float floatx4;

__device__ __forceinline__ void load_lds16(const void* g, void* l) {
  __builtin_amdgcn_global_load_lds((const __attribute__((address_space(1))) void*)g,
                                   (__attribute__((address_space(3))) void*)l,
                                   16, 0, 0);
}

__device__ __forceinline__ unsigned short bf16bits(float f) {
  __hip_bfloat16 h = __float2bfloat16(f);
  return *reinterpret_cast<unsigned short*>(&h);
}

// ---------------- k_pad: x fp32 -> xp bf16 with zero halo (4 ch/thread) ----------------
__global__ __launch_bounds__(256) void k_pad(const float* __restrict__ x,
                                             uint2* __restrict__ xp) {
  const int tid = threadIdx.x;
  const int sub = tid >> 6, c4 = tid & 63;       // pixel-in-block, channel-quad
  const int pp  = blockIdx.x * 4 + sub;          // 0 .. 4*98*98-1
  const int b   = pp / (HP * HP);
  const int r   = pp % (HP * HP);
  const int y   = r / HP, xq = r % HP;
  uint2 o = {0u, 0u};
  if (y >= 1 && y <= H && xq >= 1 && xq <= W) {
    const float4 v = *(const float4*)(x + ((size_t)((b * H + (y - 1)) * W + (xq - 1))) * C + c4 * 4);
    o.x = (uint32_t)bf16bits(v.x) | ((uint32_t)bf16bits(v.y) << 16);
    o.y = (uint32_t)bf16bits(v.z) | ((uint32_t)bf16bits(v.w) << 16);
  }
  xp[(size_t)pp * 64 + c4] = o;
}

// ---------------- k_omw: omk [9*256][27] -> wom [32][2304] bf16, zero-pad rows ----------------
__global__ __launch_bounds__(256) void k_omw(const float* __restrict__ omk,
                                             __hip_bfloat16* __restrict__ wom) {
  const int kk = blockIdx.x;   // 0..8
  const int oc = blockIdx.y;   // 0..31
  const int c  = threadIdx.x;  // 0..255
  float v = (oc < 27) ? omk[(size_t)(kk * 256 + c) * 27 + oc] : 0.f;
  wom[(size_t)oc * KC + kk * 256 + c] = __float2bfloat16(v);
}

// ---------------- k_wt: kern [KC][F] fp32 -> wt [F][KC] bf16 via LDS transpose ----------------
__global__ __launch_bounds__(256) void k_wt(const float* __restrict__ kern,
                                            __hip_bfloat16* __restrict__ wt) {
  __shared__ float t[64][65];
  const int kc0 = blockIdx.x * 64, f0 = blockIdx.y * 64;
  const int rr = threadIdx.x >> 6, cc = threadIdx.x & 63;
#pragma unroll
  for (int i = 0; i < 16; ++i) {
    const int row = rr * 16 + i;
    t[row][cc] = kern[(size_t)(kc0 + row) * F + f0 + cc];   // coalesced 256B
  }
  __syncthreads();
#pragma unroll
  for (int i = 0; i < 16; ++i) {
    const int frow = rr * 16 + i;
    wt[(size_t)(f0 + frow) * KC + kc0 + cc] = __float2bfloat16(t[cc][frow]);  // coalesced 128B
  }
}

// ---------------- k_omgemm: implicit-im2col MFMA GEMM, tile 128(M) x 32(N), split-K x6 ----------------
__global__ __launch_bounds__(256) void k_omgemm(const __hip_bfloat16* __restrict__ xp,
                                                const __hip_bfloat16* __restrict__ wom,
                                                float* __restrict__ pOm) {
  __shared__ __align__(16) char lds[10240];  // A [128][32]bf16 @0 (8KB), B [32][32]bf16 @8192 (2KB)
  const int tid  = threadIdx.x;
  const int m0   = blockIdx.x * 128;
  const int s    = blockIdx.y;               // K-split 0..5
  const int lane = tid & 63, wave = tid >> 6;
  const int quad = lane >> 4, l16 = lane & 15;

  const int kp = tid & 3;
  const __hip_bfloat16* abase[2];
#pragma unroll
  for (int j = 0; j < 2; ++j) {
    const int row = (tid >> 2) + j * 64;
    const int p = m0 + row;
    const int b = p / (H * W);
    const int hw = p % (H * W);
    const int h = hw / W, w = hw % W;
    abase[j] = (const __hip_bfloat16*)xp + ((size_t)(b * HP + h) * HP + w) * C + kp * 8;
  }
  const __hip_bfloat16* bbase = wom + (size_t)(tid >> 2) * KC + kp * 8;  // tid<128 only

  floatx4 acc[2][2];
#pragma unroll
  for (int i = 0; i < 2; ++i)
#pragma unroll
    for (int j = 0; j < 2; ++j) acc[i][j] = (floatx4){0.f, 0.f, 0.f, 0.f};

  const int kbeg = s * 384;
#pragma unroll 1
  for (int k0 = kbeg; k0 < kbeg + 384; k0 += 32) {
    const int kk = k0 >> 8;                 // 32-chunks never straddle a kk boundary
    const int c0 = k0 & 255;
    const int kh = kk / 3, kw = kk % 3;
    const int aoff = (kh * HP + kw) * C + c0;  // wave-uniform

    __syncthreads();
    load_lds16(abase[0] + aoff, &lds[tid * 16]);
    load_lds16(abase[1] + aoff, &lds[4096 + tid * 16]);
    if (tid < 128) load_lds16(bbase + k0, &lds[8192 + tid * 16]);
    __syncthreads();

    bf16x8 af[2], bfr[2];
#pragma unroll
    for (int mt = 0; mt < 2; ++mt)
      af[mt] = *(const bf16x8*)&lds[((wave * 32 + mt * 16 + l16) * 32 + quad * 8) * 2];
#pragma unroll
    for (int nt = 0; nt < 2; ++nt)
      bfr[nt] = *(const bf16x8*)&lds[8192 + ((nt * 16 + l16) * 32 + quad * 8) * 2];
#pragma unroll
    for (int mt = 0; mt < 2; ++mt)
#pragma unroll
      for (int nt = 0; nt < 2; ++nt)
        acc[mt][nt] = __builtin_amdgcn_mfma_f32_16x16x32_bf16(af[mt], bfr[nt], acc[mt][nt], 0, 0, 0);
  }

#pragma unroll
  for (int mt = 0; mt < 2; ++mt)
#pragma unroll
    for (int nt = 0; nt < 2; ++nt) {
      const int gm = m0 + wave * 32 + mt * 16 + quad * 4;
      const int gn = nt * 16 + l16;
#pragma unroll
      for (int r = 0; r < 4; ++r)
        __hip_atomic_fetch_add(&pOm[(size_t)(gm + r) * 32 + gn], acc[mt][nt][r],
                               __ATOMIC_RELAXED, __HIP_MEMORY_SCOPE_AGENT);
    }
}

// ---------------- k_sample: 4 pixels/block, 4 channels/thread (uint2 = 4 bf16) ----------------
__global__ __launch_bounds__(256) void k_sample(const uint2* __restrict__ xp,
                                                const float* __restrict__ pOm,
                                                const float* __restrict__ om_bias,
                                                uint2* __restrict__ cols) {
  const int tid = threadIdx.x;
  const int sub = tid >> 6, cid = tid & 63;        // pixel-in-block, channel-quad
  const int p   = blockIdx.x * 4 + sub;
  const int b   = p / (H * W);
  const int hw  = p % (H * W);
  const int h = hw / W, w = hw % W;

  __shared__ float s_py[4][9], s_px[4][9], s_m[4][9];
  if (cid < 9) {
    const int k = cid;
    const float dy = om_bias[2 * k]     + pOm[(size_t)p * 32 + 2 * k];
    const float dx = om_bias[2 * k + 1] + pOm[(size_t)p * 32 + 2 * k + 1];
    const float mv = om_bias[18 + k]    + pOm[(size_t)p * 32 + 18 + k];
    s_py[sub][k] = (float)(h - 1 + k / 3) + dy;
    s_px[sub][k] = (float)(w - 1 + k % 3) + dx;
    s_m[sub][k]  = 2.f / (1.f + __expf(-mv));
  }
  __syncthreads();

  const uint2* __restrict__ xb = xp + (size_t)b * (HP * HP * 64) + cid;
  uint2* __restrict__ ob = cols + (size_t)p * (KC / 4) + cid;

#pragma unroll 1
  for (int k = 0; k < 9; ++k) {
    const float py = s_py[sub][k], px = s_px[sub][k], m = s_m[sub][k];
    const float y0f = floorf(py), x0f = floorf(px);
    const float fy = py - y0f, fx = px - x0f;
    const int y0 = (int)y0f, x0 = (int)x0f;
    float v0 = 0.f, v1 = 0.f, v2 = 0.f, v3 = 0.f;
#pragma unroll
    for (int dy2 = 0; dy2 < 2; ++dy2) {
#pragma unroll
      for (int dx2 = 0; dx2 < 2; ++dx2) {
        const int yi = y0 + dy2, xi = x0 + dx2;
        const bool valid = (yi >= 0) & (yi < H) & (xi >= 0) & (xi < W);
        const float wgt = valid ? (dy2 ? fy : 1.f - fy) * (dx2 ? fx : 1.f - fx) : 0.f;
        const int yc = min(max(yi + 1, 0), HP - 1);
        const int xc = min(max(xi + 1, 0), HP - 1);
        const uint2 v = xb[(size_t)(yc * HP + xc) * 64];
        v0 += wgt * __uint_as_float(v.x << 16);
        v1 += wgt * __uint_as_float(v.x & 0xffff0000u);
        v2 += wgt * __uint_as_float(v.y << 16);
        v3 += wgt * __uint_as_float(v.y & 0xffff0000u);
      }
    }
    uint2 o;
    o.x = (uint32_t)bf16bits(v0 * m) | ((uint32_t)bf16bits(v1 * m) << 16);
    o.y = (uint32_t)bf16bits(v2 * m) | ((uint32_t)bf16bits(v3 * m) << 16);
    ob[k * 64] = o;
  }
}

// ---------------- k_gemm: bf16 MFMA GEMM, 96(M) x 128(N) tile, 768 blocks = 3.0/CU ----------------
__global__ __launch_bounds__(256) void k_gemm(const __hip_bfloat16* __restrict__ A,
                                              const __hip_bfloat16* __restrict__ Bt,
                                              const float* __restrict__ bias,
                                              float* __restrict__ out) {
  __shared__ __align__(16) char lds[14336];   // A [96][32] @0 (6KB), B [128][32] @6144 (8KB)

  const int tid  = threadIdx.x;
  const int m0   = blockIdx.x * 96;
  const int n0   = blockIdx.y * 128;
  const int lane = tid & 63, wave = tid >> 6;
  const int wm = wave & 1, wn = wave >> 1;    // wave = 48M x 64N
  const int quad = lane >> 4, l16 = lane & 15;

  floatx4 acc[3][4];
#pragma unroll
  for (int i = 0; i < 3; ++i)
#pragma unroll
    for (int j = 0; j < 4; ++j) acc[i][j] = (floatx4){0.f, 0.f, 0.f, 0.f};

#pragma unroll 1
  for (int k0 = 0; k0 < KC; k0 += 32) {
    __syncthreads();
    {
      const int row = tid >> 2, kp = tid & 3;
      load_lds16(A + (size_t)(m0 + row) * KC + k0 + kp * 8, &lds[tid * 16]);            // A rows 0..63
      if (tid < 128)
        load_lds16(A + (size_t)(m0 + 64 + row) * KC + k0 + kp * 8, &lds[4096 + tid * 16]); // A rows 64..95
      load_lds16(Bt + (size_t)(n0 + row) * KC + k0 + kp * 8, &lds[6144 + tid * 16]);    // B rows 0..63
      load_lds16(Bt + (size_t)(n0 + 64 + row) * KC + k0 + kp * 8, &lds[10240 + tid * 16]); // B rows 64..127
    }
    __syncthreads();

    bf16x8 af[3], bfr[4];
#pragma unroll
    for (int mt = 0; mt < 3; ++mt)
      af[mt] = *(const bf16x8*)&lds[((wm * 48 + mt * 16 + l16) * 32 + quad * 8) * 2];
#pragma unroll
    for (int nt = 0; nt < 4; ++nt)
      bfr[nt] = *(const bf16x8*)&lds[6144 + ((wn * 64 + nt * 16 + l16) * 32 + quad * 8) * 2];
#pragma unroll
    for (int mt = 0; mt < 3; ++mt)
#pragma unroll
      for (int nt = 0; nt < 4; ++nt)
        acc[mt][nt] = __builtin_amdgcn_mfma_f32_16x16x32_bf16(af[mt], bfr[nt], acc[mt][nt], 0, 0, 0);
  }

  // epilogue: C/D layout col=lane&15, row=quad*4+reg, + bias
#pragma unroll
  for (int mt = 0; mt < 3; ++mt) {
#pragma unroll
    for (int nt = 0; nt < 4; ++nt) {
      const int gm = m0 + wm * 48 + mt * 16 + quad * 4;
      const int gn = n0 + wn * 64 + nt * 16 + l16;
      const float bs = bias[gn];
#pragma unroll
      for (int r = 0; r < 4; ++r)
        out[(size_t)(gm + r) * F + gn] = acc[mt][nt][r] + bs;
    }
  }
}

extern "C" void kernel_launch(void* const* d_in, const int* in_sizes, int n_in,
                              void* d_out, int out_size, void* d_ws, size_t ws_size,
                              hipStream_t stream) {
  const float* x    = (const float*)d_in[0];   // [4,96,96,256]
  const float* omk  = (const float*)d_in[1];   // [3,3,256,27]
  const float* omb  = (const float*)d_in[2];   // [27]
  const float* kern = (const float*)d_in[3];   // [2304,256]
  const float* bias = (const float*)d_in[4];   // [256]
  float* out = (float*)d_out;                  // [4,96,96,256]

  char* ws = (char*)d_ws;
  size_t off = 0;
  __hip_bfloat16* wt   = (__hip_bfloat16*)(ws + off); off += (size_t)F * KC * 2;           // 1,179,648
  __hip_bfloat16* xp   = (__hip_bfloat16*)(ws + off); off += (size_t)4 * HP * HP * C * 2;  // 19,668,992
  __hip_bfloat16* wom  = (__hip_bfloat16*)(ws + off); off += (size_t)32 * KC * 2;          // 147,456
  float*          pOm  = (float*)(ws + off);          off += (size_t)NP * 32 * 4;          // 4,718,592
  __hip_bfloat16* cols = (__hip_bfloat16*)(ws + off);                                      // 169,869,312

  k_pad   <<<dim3(4 * HP * HP / 4), 256, 0, stream>>>(x, (uint2*)xp);
  k_omw   <<<dim3(9, 32),           256, 0, stream>>>(omk, wom);
  k_wt    <<<dim3(KC / 64, F / 64), 256, 0, stream>>>(kern, wt);
  hipMemsetAsync(pOm, 0, (size_t)NP * 32 * 4, stream);
  k_omgemm<<<dim3(NP / 128, 6),     256, 0, stream>>>(xp, wom, pOm);
  k_sample<<<dim3(NP / 4),          256, 0, stream>>>((const uint2*)xp, pOm, omb, (uint2*)cols);
  k_gemm  <<<dim3(NP / 96, F / 128), 256, 0, stream>>>(cols, wt, bias, out);
}